// Round 2
// 380.718 us; speedup vs baseline: 1.0871x; 1.0871x over previous
//
#include <hip/hip_runtime.h>
#include <stdint.h>
#include <stddef.h>

#define B_ 8
#define D_ 128
#define T_ 32768
#define C_ 64
#define NCH_ 64       // t-chunks per batch in k1; Tc = 512

typedef __bf16 bf16;
typedef __bf16 bf16x4 __attribute__((ext_vector_type(4)));
typedef __bf16 bf16x8 __attribute__((ext_vector_type(8)));
typedef float f32x4 __attribute__((ext_vector_type(4)));
typedef float f32x16 __attribute__((ext_vector_type(16)));

__device__ __forceinline__ f32x16 zero16() {
  f32x16 z;
#pragma unroll
  for (int i = 0; i < 16; ++i) z[i] = 0.f;
  return z;
}

// ---------------------------------------------------------------------------
// K0: zero G[b][128][128] and r[b][128] (ws is poisoned before each call)
// ---------------------------------------------------------------------------
__global__ __launch_bounds__(256) void k0_zero(float* __restrict__ p, int n)
{
  int i = blockIdx.x * 256 + threadIdx.x;
  if (i < n) p[i] = 0.f;
}

// ---------------------------------------------------------------------------
// K1: Gram partials Gpart[blk] = x1_chunk x1_chunk^T via LDS-staged tiles
//     (1x HBM read). NO G atomics: each block owns a 64 KB fp32 partial slot
//     (split-K partials; k2 reduces). Row-sums r keep cheap atomics (65K ops).
//     96 extra blocks: fold wk'=we@wk(+bk'), wv'=wf@wv(+bv'), wo -> bf16.
//     Fallback (gpart==nullptr): old atomicAdd-into-G path.
// ---------------------------------------------------------------------------
__global__ __launch_bounds__(256, 4) void k1_gram(
    const float* __restrict__ x1,
    const float* __restrict__ we, const float* __restrict__ wk,
    const float* __restrict__ bk, const float* __restrict__ be,
    const float* __restrict__ wf, const float* __restrict__ wv,
    const float* __restrict__ bv, const float* __restrict__ bfv,
    const float* __restrict__ wo,
    float* __restrict__ G, float* __restrict__ r,
    float* __restrict__ wkp, float* __restrict__ wvp,
    float* __restrict__ bkp, float* __restrict__ bvp,
    bf16* __restrict__ wobf,
    float* __restrict__ gpart)
{
  const int blk = blockIdx.x;
  const int tid = threadIdx.x;
  const int ngram = B_ * NCH_;   // 512

  if (blk >= ngram) {
    const int wb = blk - ngram;  // 0..95
    if (wb < 64) {               // folded weights
      const float* wa  = (wb < 32) ? we : wf;
      const float* wb2 = (wb < 32) ? wk : wv;
      float* outw      = (wb < 32) ? wkp : wvp;
      const int idx = (wb & 31) * 256 + tid;   // 0..8191
      const int o = idx >> 7, d = idx & 127;
      float s = 0.f;
      for (int c = 0; c < 64; ++c) s += wa[o * 64 + c] * wb2[c * 128 + d];
      outw[idx] = s;
      if (tid < 64) {
        if (wb == 0) {
          float t = 0.f;
          for (int c = 0; c < 64; ++c) t += we[tid * 64 + c] * bk[c];
          bkp[tid] = t + be[tid];
        } else if (wb == 32) {
          float t = 0.f;
          for (int c = 0; c < 64; ++c) t += wf[tid * 64 + c] * bv[c];
          bvp[tid] = t + bfv[tid];
        }
      }
    } else {                     // wo -> bf16 (8192 elements over 32 blocks)
      const int idx = (wb - 64) * 256 + tid;
      wobf[idx] = (bf16)wo[idx];
    }
    return;
  }

  __shared__ bf16 x_s[128 * 72];   // [row][kcol], pad 64->72 (16B-aligned rows)

  const int b  = blk / NCH_;
  const int ch = blk & (NCH_ - 1);
  const int t0 = ch * (T_ / NCH_);           // Tc = 512
  const int wave = tid >> 6, lane = tid & 63;
  const int lrow = lane & 31, lk = lane >> 5;
  const int qa = wave >> 1, qb = wave & 1;   // wave owns 64x64 quadrant

  const float* xb = x1 + (size_t)b * D_ * T_;

  f32x16 acc00 = zero16(), acc01 = zero16(), acc10 = zero16(), acc11 = zero16();
  float rsum = 0.f;

  const int scol = (tid & 15) * 4;           // staging col for this thread
  const int srow0 = tid >> 4;                // staging row base (0..15)

  const bf16* A0  = &x_s[(64 * qa + lrow) * 72 + 8 * lk];
  const bf16* A1  = A0 + 32 * 72;
  const bf16* Bb0 = &x_s[(64 * qb + lrow) * 72 + 8 * lk];
  const bf16* Bb1 = Bb0 + 32 * 72;

  for (int s = 0; s < 8; ++s) {              // 8 stages of 64 t-cols
    const int tb = t0 + s * 64;
    if (s) __syncthreads();                  // prev-stage reads done before overwrite
#pragma unroll
    for (int it = 0; it < 8; ++it) {
      const int row = it * 16 + srow0;
      f32x4 v = *(const f32x4*)(xb + (size_t)row * T_ + tb + scol);
      bf16x4 h;
#pragma unroll
      for (int j = 0; j < 4; ++j) h[j] = (bf16)v[j];
      *(bf16x4*)&x_s[row * 72 + scol] = h;
    }
    __syncthreads();
#pragma unroll
    for (int k = 0; k < 4; ++k) {
      bf16x8 fa0 = *(const bf16x8*)(A0 + 16 * k);
      bf16x8 fa1 = *(const bf16x8*)(A1 + 16 * k);
      bf16x8 fb0 = *(const bf16x8*)(Bb0 + 16 * k);
      bf16x8 fb1 = *(const bf16x8*)(Bb1 + 16 * k);
      bf16x8 own = qb ? fa1 : fa0;           // wave w sums rows 32w..32w+31
#pragma unroll
      for (int j = 0; j < 8; ++j) rsum += (float)own[j];
      acc00 = __builtin_amdgcn_mfma_f32_32x32x16_bf16(fa0, fb0, acc00, 0, 0, 0);
      acc01 = __builtin_amdgcn_mfma_f32_32x32x16_bf16(fa0, fb1, acc01, 0, 0, 0);
      acc10 = __builtin_amdgcn_mfma_f32_32x32x16_bf16(fa1, fb0, acc10, 0, 0, 0);
      acc11 = __builtin_amdgcn_mfma_f32_32x32x16_bf16(fa1, fb1, acc11, 0, 0, 0);
    }
  }

  if (gpart) {
    // split-K partial: this block owns its own 64 KB slot -> plain stores
    float* gp = gpart + (size_t)blk * 16384;
#pragma unroll
    for (int rr = 0; rr < 16; ++rr) {
      const int rloc = (rr & 3) + 8 * (rr >> 2) + 4 * lk;   // C/D row map
      const int r0 = 64 * qa + rloc, r1 = 64 * qa + 32 + rloc;
      const int c0 = 64 * qb + lrow, c1 = 64 * qb + 32 + lrow;
      gp[r0 * 128 + c0] = acc00[rr];
      gp[r0 * 128 + c1] = acc01[rr];
      gp[r1 * 128 + c0] = acc10[rr];
      gp[r1 * 128 + c1] = acc11[rr];
    }
  } else {
    float* gb = G + (size_t)b * 16384;
#pragma unroll
    for (int rr = 0; rr < 16; ++rr) {
      const int rloc = (rr & 3) + 8 * (rr >> 2) + 4 * lk;
      const int r0 = 64 * qa + rloc, r1 = 64 * qa + 32 + rloc;
      const int c0 = 64 * qb + lrow, c1 = 64 * qb + 32 + lrow;
      atomicAdd(&gb[r0 * 128 + c0], acc00[rr]);
      atomicAdd(&gb[r0 * 128 + c1], acc01[rr]);
      atomicAdd(&gb[r1 * 128 + c0], acc10[rr]);
      atomicAdd(&gb[r1 * 128 + c1], acc11[rr]);
    }
  }
  float rtot = rsum + __shfl_xor(rsum, 32, 64);
  if (lk == 0) atomicAdd(&r[b * 128 + 32 * wave + lrow], rtot);
}

// ---------------------------------------------------------------------------
// K2: G[b] = sum over NCH_ partials. f32x4 per thread, fully coalesced.
//     grid 128 x 256 thr: each thread sums 64 strided f32x4 (1 KB in flight).
// ---------------------------------------------------------------------------
__global__ __launch_bounds__(256) void k2_reduce(
    const float* __restrict__ gpart, float* __restrict__ G)
{
  const int g4 = blockIdx.x * 256 + threadIdx.x;  // 0..32767 (4 floats each)
  const int b = g4 >> 12;                          // 4096 f32x4 per batch
  const int e4 = g4 & 4095;
  const f32x4* p = (const f32x4*)(gpart + ((size_t)b * NCH_) * 16384) + e4;
  f32x4 s = {0.f, 0.f, 0.f, 0.f};
#pragma unroll
  for (int ch = 0; ch < NCH_; ++ch) s += p[(size_t)ch * 4096];
  *((f32x4*)G + g4) = s;
}

// ---------------------------------------------------------------------------
// K3: per (b, c): S[c,:] = wq_c G wk'^T + exact bias terms (via r),
//     P = softmax(S/8), att_w[c,:] = P @ wv' (bf16), att_b[c] = P @ bv'
// ---------------------------------------------------------------------------
__global__ __launch_bounds__(128) void k3_softmax(
    const float* __restrict__ wq, const float* __restrict__ bq,
    const float* __restrict__ G, const float* __restrict__ r,
    const float* __restrict__ wkp, const float* __restrict__ wvp,
    const float* __restrict__ bkp, const float* __restrict__ bvp,
    bf16* __restrict__ attw, float* __restrict__ attb)
{
  const int b = blockIdx.x >> 6, c = blockIdx.x & 63;
  const int tid = threadIdx.x;
  __shared__ float sM[128], sR[128], sQ[128], sP[64];
  __shared__ float sRed;

  const float* Gb = G + (size_t)b * 16384;
  const float* wqc = wq + c * 128;

  const float rv = r[b * 128 + tid];
  sR[tid] = rv;
  float m = 0.f;
  for (int j = 0; j < 128; ++j) m += wqc[j] * Gb[j * 128 + tid];
  sM[tid] = m;
  sQ[tid] = wqc[tid] * rv;
  __syncthreads();

  if (tid < 64) {
    float q2 = sQ[tid] + sQ[tid + 64];
#pragma unroll
    for (int off = 32; off; off >>= 1) q2 += __shfl_xor(q2, off, 64);
    if (tid == 0) sRed = q2;
  }
  __syncthreads();
  const float qr = sRed;
  const float bqc = bq[c];

  if (tid < 64) {
    const int k = tid;
    float s = 0.f, wkr = 0.f;
    for (int i = 0; i < 128; ++i) {
      const float w = wkp[k * 128 + i];
      s += sM[i] * w;
      wkr += sR[i] * w;
    }
    const float bk2 = bkp[k];
    float logit = (s + bqc * wkr + bk2 * qr + (float)T_ * bqc * bk2) * 0.125f;
    float mx = logit;
#pragma unroll
    for (int off = 32; off; off >>= 1) mx = fmaxf(mx, __shfl_xor(mx, off, 64));
    const float e = __expf(logit - mx);
    float sum = e;
#pragma unroll
    for (int off = 32; off; off >>= 1) sum += __shfl_xor(sum, off, 64);
    sP[k] = e / sum;
  }
  __syncthreads();

  {
    float aw = 0.f;
    for (int k = 0; k < 64; ++k) aw += sP[k] * wvp[k * 128 + tid];
    attw[((size_t)b * 64 + c) * 128 + tid] = (bf16)aw;
  }
  if (tid < 64) {
    float pb = sP[tid] * bvp[tid];
#pragma unroll
    for (int off = 32; off; off >>= 1) pb += __shfl_xor(pb, off, 64);
    if (tid == 0) attb[b * 64 + c] = pb;
  }
}

// ---------------------------------------------------------------------------
// K4: fused output, barrier-free main path. Per (b, 128-wide t-tile):
//   stage1 B-frags read DIRECTLY from global x1 (coalesced dword loads),
//   M1 = relu(attw@x + ab) -> small [t][c] LDS (pad 72; within-lane rows
//   only -> no barrier), stage2 out = wobf@m1 + bo, masked fp32 store.
// ---------------------------------------------------------------------------
__global__ __launch_bounds__(256, 4) void k4_out(
    const float* __restrict__ x1, const float* __restrict__ mask,
    const bf16* __restrict__ wobf, const float* __restrict__ bo,
    const bf16* __restrict__ attw, const float* __restrict__ attb,
    float* __restrict__ out)
{
  __shared__ bf16 m1[128 * 72];   // [t][c], pad 64->72
  __shared__ float bo_s[128];
  __shared__ float ab_s[64];

  const int b = blockIdx.x >> 8;           // 256 tiles per batch
  const int t0 = (blockIdx.x & 255) << 7;
  const int tid = threadIdx.x;
  const int wave = tid >> 6, lane = tid & 63;
  const int lrow = lane & 31, lk = lane >> 5;
  const int tcol = 32 * wave + lrow;

  if (tid < 128) bo_s[tid] = bo[tid];
  if (tid < 64) ab_s[tid] = attb[b * 64 + tid];
  __syncthreads();                          // only barrier (tiny staging)

  const float* xc = x1 + (size_t)b * D_ * T_ + t0 + tcol;   // column base
  const bf16* awb = attw + (size_t)b * 8192;

  // ---- stage 1: M1[c][t] = attw[c][d] * x[d][t]
  f32x16 p0 = zero16(), p1 = zero16();
#pragma unroll
  for (int k0 = 0; k0 < 8; ++k0) {
    bf16x8 a0 = *(const bf16x8*)(awb + (size_t)lrow * 128 + 16 * k0 + 8 * lk);
    bf16x8 a1 = *(const bf16x8*)(awb + (size_t)(32 + lrow) * 128 + 16 * k0 + 8 * lk);
    bf16x8 bx;
#pragma unroll
    for (int j = 0; j < 8; ++j)
      bx[j] = (bf16)xc[(size_t)(16 * k0 + 8 * lk + j) * T_];
    p0 = __builtin_amdgcn_mfma_f32_32x32x16_bf16(a0, bx, p0, 0, 0, 0);
    p1 = __builtin_amdgcn_mfma_f32_32x32x16_bf16(a1, bx, p1, 0, 0, 0);
  }
  bf16* mrow = &m1[tcol * 72];              // this lane's own t-row
#pragma unroll
  for (int rr = 0; rr < 16; ++rr) {
    const int row = (rr & 3) + 8 * (rr >> 2) + 4 * lk;
    mrow[row]      = (bf16)fmaxf(p0[rr] + ab_s[row], 0.f);
    mrow[32 + row] = (bf16)fmaxf(p1[rr] + ab_s[32 + row], 0.f);
  }

  // ---- stage 2: out[d][t] = wobf[d][c] * m1[c][t] (own row, no barrier)
  f32x16 q0 = zero16(), q1 = zero16(), q2 = zero16(), q3 = zero16();
#pragma unroll
  for (int k0 = 0; k0 < 4; ++k0) {
    bf16x8 bm = *(const bf16x8*)(mrow + 16 * k0 + 8 * lk);
    bf16x8 w0 = *(const bf16x8*)(wobf + (size_t)(lrow) * 64 + 16 * k0 + 8 * lk);
    bf16x8 w1 = *(const bf16x8*)(wobf + (size_t)(32 + lrow) * 64 + 16 * k0 + 8 * lk);
    bf16x8 w2 = *(const bf16x8*)(wobf + (size_t)(64 + lrow) * 64 + 16 * k0 + 8 * lk);
    bf16x8 w3 = *(const bf16x8*)(wobf + (size_t)(96 + lrow) * 64 + 16 * k0 + 8 * lk);
    q0 = __builtin_amdgcn_mfma_f32_32x32x16_bf16(w0, bm, q0, 0, 0, 0);
    q1 = __builtin_amdgcn_mfma_f32_32x32x16_bf16(w1, bm, q1, 0, 0, 0);
    q2 = __builtin_amdgcn_mfma_f32_32x32x16_bf16(w2, bm, q2, 0, 0, 0);
    q3 = __builtin_amdgcn_mfma_f32_32x32x16_bf16(w3, bm, q3, 0, 0, 0);
  }

  const float mv = mask[(size_t)b * T_ + t0 + tcol];
  float* ob = out + (size_t)b * D_ * T_ + t0 + tcol;
#pragma unroll
  for (int rr = 0; rr < 16; ++rr) {
    const int row = (rr & 3) + 8 * (rr >> 2) + 4 * lk;
    ob[(size_t)(row) * T_]      = (q0[rr] + bo_s[row]) * mv;
    ob[(size_t)(32 + row) * T_] = (q1[rr] + bo_s[32 + row]) * mv;
    ob[(size_t)(64 + row) * T_] = (q2[rr] + bo_s[64 + row]) * mv;
    ob[(size_t)(96 + row) * T_] = (q3[rr] + bo_s[96 + row]) * mv;
  }
}

// ---------------------------------------------------------------------------
// Workspace: G[512K] r[4K] wkp/wvp[64K] bkp/bvp/attb small, attw 128K(bf16),
// wobf 16K(bf16) ~0.75 MB, then Gpart 512*64KB = 33.5 MB (split-K partials).
// Fallback to atomic path if ws too small.
// ---------------------------------------------------------------------------
extern "C" void kernel_launch(void* const* d_in, const int* in_sizes, int n_in,
                              void* d_out, int out_size, void* d_ws, size_t ws_size,
                              hipStream_t stream)
{
  const float* x1   = (const float*)d_in[0];
  // d_in[1] = x2 (unused in encoder stage)
  const float* mask = (const float*)d_in[2];
  const float* wq   = (const float*)d_in[3];
  const float* bq   = (const float*)d_in[4];
  const float* wk   = (const float*)d_in[5];
  const float* bk   = (const float*)d_in[6];
  const float* wv   = (const float*)d_in[7];
  const float* bv   = (const float*)d_in[8];
  const float* we   = (const float*)d_in[9];
  const float* be   = (const float*)d_in[10];
  const float* wf   = (const float*)d_in[11];
  const float* bfv  = (const float*)d_in[12];
  const float* wo   = (const float*)d_in[13];
  const float* bo   = (const float*)d_in[14];
  float* out = (float*)d_out;

  char* base = (char*)d_ws;
  size_t off = 0;
  float* G    = (float*)(base + off); off += (size_t)B_ * 16384 * 4;
  float* r    = (float*)(base + off); off += (size_t)B_ * 128 * 4;
  float* wkp  = (float*)(base + off); off += 8192 * 4;
  float* wvp  = (float*)(base + off); off += 8192 * 4;
  float* bkp  = (float*)(base + off); off += 64 * 4;
  float* bvp  = (float*)(base + off); off += 64 * 4;
  float* attb = (float*)(base + off); off += (size_t)B_ * 64 * 4;
  bf16* attw  = (bf16*)(base + off);  off += (size_t)B_ * 64 * 128 * 2;
  bf16* wobf  = (bf16*)(base + off);  off += 8192 * 2;
  // 16B-align Gpart (f32x4 loads in k2)
  off = (off + 15) & ~(size_t)15;
  float* gpart = (float*)(base + off);
  const size_t need = off + (size_t)B_ * NCH_ * 16384 * 4;
  const bool use_part = (ws_size >= need);
  if (!use_part) gpart = nullptr;

  const int nzero = B_ * 16384 + B_ * 128;   // G + r contiguous
  k0_zero<<<(nzero + 255) / 256, 256, 0, stream>>>(G, nzero);
  k1_gram<<<B_ * NCH_ + 96, 256, 0, stream>>>(
      x1, we, wk, bk, be, wf, wv, bv, bfv, wo,
      G, r, wkp, wvp, bkp, bvp, wobf, gpart);
  if (use_part)
    k2_reduce<<<(B_ * 16384) / (256 * 4), 256, 0, stream>>>(gpart, G);
  k3_softmax<<<B_ * 64, 128, 0, stream>>>(wq, bq, G, r, wkp, wvp, bkp, bvp, attw, attb);
  k4_out<<<B_ * (T_ / 128), 256, 0, stream>>>(x1, mask, wobf, bo, attw, attb, out);
}